// Round 8
// baseline (330.232 us; speedup 1.0000x reference)
//
#include <hip/hip_runtime.h>
#include <hip/hip_bf16.h>

// SpatialCrossAttention (BEVFormer SCA) fused pipeline for MI355X/gfx950.
//  K0 detect  : infer bev_mask storage layout (u8 / i32 / f32)
//  K1 hit     : hit[c][q], invcnt[q]
//  K2 prep    : bf16 W-fragment tables for the 3 GEMMs (+ concat bias)
//  G1 gemm<0> : vproj = value @ w_value + b_value -> FP8 e4m3 [139200][256]
//               BARRIER-FREE direct-load GEMM (operand-swapped MFMA, no LDS)
//  G2 gemm<1> : offattn = query @ [w_off|w_attn] + bias -> f32 [10000][192]
//  K4 sample  : fused softmax + bilinear gather (HW fp8 cvt) + cam-average
//  G3 gemm<2> : out = slots @ w_out + b_out + query -> d_out f32

typedef __attribute__((ext_vector_type(8))) short short8;
typedef __attribute__((ext_vector_type(4))) float f32x4;
typedef __attribute__((ext_vector_type(2))) float floatx2;

__device__ __forceinline__ short f2bf(float f) {
    union { float f; unsigned u; } c; c.f = f;
    unsigned u = c.u;
    unsigned r = (u + 0x7FFFu + ((u >> 16) & 1u)) >> 16;  // RNE
    return (short)r;
}

// ---- fp8 e4m3fn decode/encode: HW cvt on gfx950, manual fallback ----
__device__ __forceinline__ float e4m3f_manual(unsigned b) {
    unsigned s = (b & 0x80u) << 24;
    unsigned e = (b >> 3) & 15u;
    unsigned m = b & 7u;
    if (e) return __uint_as_float(s | ((e + 120u) << 23) | (m << 20));
    return __uint_as_float(s | __float_as_uint((float)m * 0x1p-9f));
}
__device__ __forceinline__ unsigned char f2e4m3_manual(float x) {
    unsigned u = __float_as_uint(x);
    unsigned s = (u >> 24) & 0x80u;
    float ax = fabsf(x);
    if (!(ax > 0x1p-10f)) return (unsigned char)s;
    if (ax >= 440.f) return (unsigned char)(s | 0x7Eu);
    unsigned au = u & 0x7FFFFFFFu;
    int e = (int)(au >> 23) - 127;
    if (e >= -6) {
        unsigned r = au + 0x7FFFFu + ((au >> 20) & 1u);
        e = (int)(r >> 23) - 127;
        unsigned m = (r >> 20) & 7u;
        if (e > 8) return (unsigned char)(s | 0x7Eu);
        return (unsigned char)(s | (unsigned)((e + 7) << 3) | m);
    } else {
        int m = (int)rintf(ax * 512.f);
        return (unsigned char)(s | (unsigned)m);
    }
}

static constexpr int QN   = 10000;
static constexpr int CAMS = 6;
static constexpr int NV   = 23200;   // 116*200
static constexpr int HH   = 116;
static constexpr int WW   = 200;
static constexpr int MROW = CAMS * NV;  // 139200

// ---------------- K0: mask layout detect ----------------
__global__ void detect_kernel(const unsigned char* __restrict__ mask, int* __restrict__ flag) {
    __shared__ unsigned s12[256], s3[256];
    unsigned o12 = 0, o3 = 0;
    for (int i = threadIdx.x; i < 65536; i += 256) {
        unsigned char b = mask[i];
        int m = i & 3;
        if (m == 1 || m == 2) o12 |= b;
        else if (m == 3) o3 |= b;
    }
    s12[threadIdx.x] = o12; s3[threadIdx.x] = o3;
    __syncthreads();
    if (threadIdx.x == 0) {
        unsigned a = 0, b = 0;
        for (int i = 0; i < 256; i++) { a |= s12[i]; b |= s3[i]; }
        *flag = a ? 0 : (b ? 2 : 1);  // 0=u8, 1=i32, 2=f32
    }
}

// ---------------- K1: hit / invcount ----------------
__global__ void hit_kernel(const void* __restrict__ mask, const int* __restrict__ flag,
                           float* __restrict__ hit, float* __restrict__ invcnt) {
    int q = blockIdx.x * 256 + threadIdx.x;
    if (q >= QN) return;
    int f = *flag;
    int cnt = 0;
    for (int c = 0; c < CAMS; c++) {
        bool any = false;
        #pragma unroll
        for (int d = 0; d < 4; d++) {
            size_t i = (size_t)(c * QN + q) * 4 + d;
            bool b;
            if (f == 0)      b = ((const unsigned char*)mask)[i] != 0;
            else if (f == 1) b = ((const int*)mask)[i] != 0;
            else             b = ((const float*)mask)[i] != 0.f;
            any |= b;
        }
        hit[c * QN + q] = any ? 1.f : 0.f;
        cnt += any ? 1 : 0;
    }
    invcnt[q] = 1.f / (float)(cnt > 0 ? cnt : 1);
}

// ---------------- K2: weight fragment tables ----------------
// entry e = ((kc*16 + nt)*64 + lane)*8 + j ;  W[kc*32 + (lane>>4)*8 + j][nt*16 + (lane&15)]
// Used as the MFMA *A-operand*: lane&15 -> n (free dim), (lane>>4)*8+j -> k.
__global__ void prep_kernel(const float* __restrict__ wv, const float* __restrict__ woff,
                            const float* __restrict__ wattn, const float* __restrict__ wout,
                            const float* __restrict__ boff, const float* __restrict__ battn,
                            short* __restrict__ tv, short* __restrict__ toa,
                            short* __restrict__ tout, float* __restrict__ biasOA) {
    int id = blockIdx.x * 256 + threadIdx.x;
    if (id < 3 * 65536) {
        int t = id >> 16;
        int e = id & 65535;
        int j = e & 7, l = (e >> 3) & 63, nt = (e >> 9) & 15, kc = e >> 13;
        int k = kc * 32 + ((l >> 4) << 3) + j;
        int col = nt * 16 + (l & 15);
        float v;
        if (t == 0)      v = wv[k * 256 + col];
        else if (t == 1) v = (col < 128) ? woff[k * 128 + col]
                               : (col < 192 ? wattn[k * 64 + (col - 128)] : 0.f);
        else             v = wout[k * 256 + col];
        short* dst = (t == 0) ? tv : (t == 1) ? toa : tout;
        dst[e] = f2bf(v);
    } else {
        int i = id - 3 * 65536;
        if (i < 192) biasOA[i] = (i < 128) ? boff[i] : battn[i - 128];
    }
}

// ---------------- GEMM: direct-load, barrier-free, operand-swapped ----------------
// out[m][n] = sum_k A[m][k] * W[k][n]  (+bias, modes as before)
// MFMA: D = Afrag(W) x Bfrag(A-rows):
//   A-operand: Wtab fragment, lane&15 -> n, (lane>>4)*8+j -> k
//   B-operand: A[m][k], lane&15 -> m, (lane>>4)*8+j -> k  (8 contiguous f32/lane)
//   D: lane holds 4 consecutive n (nt*16 + (lane>>4)*4 + i) for m = mBase+(lane&15)
// Per wave: 16 rows x 256 cols, acc[16] f32x4, NO LDS, NO barriers.
// MODE 0: out fp8 e4m3 packed u32 (vproj), MODE 1: f32 192 cols, MODE 2: f32+resid.
template <int MODE>
__global__ __launch_bounds__(256)
void gemm_direct(const float* __restrict__ A, const short* __restrict__ Wtab,
                 const float* __restrict__ bias, const float* __restrict__ resid,
                 void* __restrict__ out, int M) {
    const int tid = threadIdx.x;
    const int l  = tid & 63;
    const int wv = tid >> 6;
    const int lr = l & 15;
    const int lg = l >> 4;
    const int mBase = (blockIdx.x * 4 + wv) * 16;
    if (mBase >= M) return;                       // wave-uniform, no barriers in kernel
    const int m = mBase + lr;

    const float* arow = A + (size_t)m * 256 + lg * 8;
    const short* wbase = Wtab + (size_t)l * 8;

    f32x4 acc[16] = {};

    #pragma unroll
    for (int kc = 0; kc < 8; kc++) {
        // B-operand: value[m][kc*32 + lg*8 .. +7] -> bf16x8
        const float4* p = (const float4*)(arow + kc * 32);
        float4 x0 = p[0], x1 = p[1];
        unsigned u0, u1, u2, u3;
        asm("v_cvt_pk_bf16_f32 %0, %1, %2" : "=v"(u0) : "v"(x0.x), "v"(x0.y));
        asm("v_cvt_pk_bf16_f32 %0, %1, %2" : "=v"(u1) : "v"(x0.z), "v"(x0.w));
        asm("v_cvt_pk_bf16_f32 %0, %1, %2" : "=v"(u2) : "v"(x1.x), "v"(x1.y));
        asm("v_cvt_pk_bf16_f32 %0, %1, %2" : "=v"(u3) : "v"(x1.z), "v"(x1.w));
        union { unsigned u[4]; short8 s8; } uu;
        uu.u[0] = u0; uu.u[1] = u1; uu.u[2] = u2; uu.u[3] = u3;
        short8 bfrag = uu.s8;

        #pragma unroll
        for (int nt = 0; nt < 16; nt++) {
            short8 af = *(const short8*)(wbase + ((size_t)(kc * 16 + nt) << 9));
            acc[nt] = __builtin_amdgcn_mfma_f32_16x16x32_bf16(af, bfrag, acc[nt], 0, 0, 0);
        }
    }

    #pragma unroll
    for (int nt = 0; nt < 16; nt++) {
        int n0 = nt * 16 + lg * 4;                // first of 4 consecutive n
        if (MODE == 1 && nt >= 12) continue;      // 192 = 12*16 cols
        float4 bv = *(const float4*)(bias + n0);
        float v0 = acc[nt][0] + bv.x, v1 = acc[nt][1] + bv.y;
        float v2 = acc[nt][2] + bv.z, v3 = acc[nt][3] + bv.w;
        if (MODE == 0) {
            unsigned pk;
#if __has_builtin(__builtin_amdgcn_cvt_pk_fp8_f32)
            pk = __builtin_amdgcn_cvt_pk_fp8_f32(v0, v1, 0, false);
            pk = __builtin_amdgcn_cvt_pk_fp8_f32(v2, v3, pk, true);
#else
            pk = (unsigned)f2e4m3_manual(v0) | ((unsigned)f2e4m3_manual(v1) << 8)
               | ((unsigned)f2e4m3_manual(v2) << 16) | ((unsigned)f2e4m3_manual(v3) << 24);
#endif
            ((unsigned*)out)[(size_t)m * 64 + (n0 >> 2)] = pk;
        } else if (MODE == 1) {
            float4 o; o.x = v0; o.y = v1; o.z = v2; o.w = v3;
            *(float4*)((float*)out + (size_t)m * 192 + n0) = o;
        } else {
            float4 rz = *(const float4*)(resid + (size_t)m * 256 + n0);
            float4 o; o.x = v0 + rz.x; o.y = v1 + rz.y; o.z = v2 + rz.z; o.w = v3 + rz.w;
            *(float4*)((float*)out + (size_t)m * 256 + n0) = o;
        }
    }
}

// ---------------- K4: fused softmax + bilinear sample (HW fp8) + cam average ----------------
// unit = 8 lanes per (q,h); lane sub handles DH elems sub*4..sub*4+3 (4 fp8 bytes).
// XCD-chunked swizzle for L2 locality.
__global__ __launch_bounds__(256)
void sample_kernel(const unsigned char* __restrict__ vproj, const float* __restrict__ offattn,
                   const float* __restrict__ refp, const float* __restrict__ hit,
                   const float* __restrict__ invcnt, float* __restrict__ slots) {
    // chunked-bijective XCD swizzle: nwg=2500, 8 XCDs -> q_=312, r=4
    int bid = blockIdx.x;
    int xcd = bid & 7, idx = bid >> 3;
    const int qch = 312, rch = 4;
    int start = (xcd < rch) ? xcd * (qch + 1) : rch * (qch + 1) + (xcd - rch) * qch;
    int wg = start + idx;

    int tid = threadIdx.x;
    int unit = wg * 32 + (tid >> 3);
    int sub = tid & 7;
    int q = unit >> 3;
    int h = unit & 7;

    const float* oa = offattn + (size_t)q * 192;
    float ox[8], oy[8], aw[8];
    float m = -1e30f;
    #pragma unroll
    for (int p = 0; p < 8; p++) {
        ox[p] = oa[h * 16 + 2 * p];
        oy[p] = oa[h * 16 + 2 * p + 1];
        float lg = oa[128 + h * 8 + p];
        aw[p] = lg;
        m = fmaxf(m, lg);
    }
    float s = 0.f;
    #pragma unroll
    for (int p = 0; p < 8; p++) { aw[p] = __expf(aw[p] - m); s += aw[p]; }
    float is = 1.f / s;
    #pragma unroll
    for (int p = 0; p < 8; p++) aw[p] *= is;

    float a0 = 0.f, a1 = 0.f, a2 = 0.f, a3 = 0.f;
    const unsigned char* vb = vproj + h * 32 + sub * 4;

    auto acc4 = [&](unsigned u, float w) {
#if __has_builtin(__builtin_amdgcn_cvt_pk_f32_fp8)
        floatx2 lo = __builtin_amdgcn_cvt_pk_f32_fp8((int)u, false);
        floatx2 hi = __builtin_amdgcn_cvt_pk_f32_fp8((int)u, true);
        a0 = fmaf(w, lo.x, a0); a1 = fmaf(w, lo.y, a1);
        a2 = fmaf(w, hi.x, a2); a3 = fmaf(w, hi.y, a3);
#else
        a0 = fmaf(w, e4m3f_manual(u & 255), a0);
        a1 = fmaf(w, e4m3f_manual((u >> 8) & 255), a1);
        a2 = fmaf(w, e4m3f_manual((u >> 16) & 255), a2);
        a3 = fmaf(w, e4m3f_manual(u >> 24), a3);
#endif
    };

    for (int c = 0; c < CAMS; c++) {
        if (hit[c * QN + q] == 0.f) continue;
        const float* rp = refp + (size_t)(c * QN + q) * 8;
        float rx[4], ry[4];
        #pragma unroll
        for (int d = 0; d < 4; d++) {
            rx[d] = rp[2 * d]     * (float)WW - 0.5f;
            ry[d] = rp[2 * d + 1] * (float)HH - 0.5f;
        }
        const unsigned char* vc = vb + (size_t)c * (NV * 256);
        #pragma unroll
        for (int p = 0; p < 8; p++) {
            float x = rx[p & 3] + ox[p];
            float y = ry[p & 3] + oy[p];
            float xf = floorf(x), yf = floorf(y);
            float fx = x - xf, fy = y - yf;
            int x0 = (int)xf, y0 = (int)yf;
            int xc0 = min(max(x0, 0), WW - 1), xc1 = min(max(x0 + 1, 0), WW - 1);
            int yc0 = min(max(y0, 0), HH - 1), yc1 = min(max(y0 + 1, 0), HH - 1);
            float vx0 = ((unsigned)x0 < (unsigned)WW) ? 1.f : 0.f;
            float vx1 = ((unsigned)(x0 + 1) < (unsigned)WW) ? 1.f : 0.f;
            float vy0 = ((unsigned)y0 < (unsigned)HH) ? 1.f : 0.f;
            float vy1 = ((unsigned)(y0 + 1) < (unsigned)HH) ? 1.f : 0.f;
            float wp = aw[p];
            float wx0 = (1.f - fx) * vx0 * wp, wx1 = fx * vx1 * wp;
            float wy0 = (1.f - fy) * vy0,      wy1 = fy * vy1;
            unsigned u00 = *(const unsigned*)(vc + (size_t)(yc0 * WW + xc0) * 256);
            unsigned u10 = *(const unsigned*)(vc + (size_t)(yc0 * WW + xc1) * 256);
            unsigned u01 = *(const unsigned*)(vc + (size_t)(yc1 * WW + xc0) * 256);
            unsigned u11 = *(const unsigned*)(vc + (size_t)(yc1 * WW + xc1) * 256);
            acc4(u00, wx0 * wy0);
            acc4(u10, wx1 * wy0);
            acc4(u01, wx0 * wy1);
            acc4(u11, wx1 * wy1);
        }
    }
    float ic = invcnt[q];
    float* sp = slots + (size_t)q * 256 + h * 32 + sub * 4;
    float4 o; o.x = a0 * ic; o.y = a1 * ic; o.z = a2 * ic; o.w = a3 * ic;
    *(float4*)sp = o;
}

extern "C" void kernel_launch(void* const* d_in, const int* in_sizes, int n_in,
                              void* d_out, int out_size, void* d_ws, size_t ws_size,
                              hipStream_t stream) {
    const float* query   = (const float*)d_in[0];
    const float* value   = (const float*)d_in[2];
    const float* refp    = (const float*)d_in[3];
    const void*  mask    = d_in[4];
    const float* w_value = (const float*)d_in[7];
    const float* b_value = (const float*)d_in[8];
    const float* w_off   = (const float*)d_in[9];
    const float* b_off   = (const float*)d_in[10];
    const float* w_attn  = (const float*)d_in[11];
    const float* b_attn  = (const float*)d_in[12];
    const float* w_out   = (const float*)d_in[13];
    const float* b_out   = (const float*)d_in[14];
    float* out = (float*)d_out;

    char* w = (char*)d_ws;
    size_t o = 0;
    auto carve = [&](size_t bytes) { size_t r = o; o = (o + bytes + 255) & ~(size_t)255; return r; };
    int*   flag    = (int*)  (w + carve(4));
    float* hitv    = (float*)(w + carve(sizeof(float) * CAMS * QN));
    float* invc    = (float*)(w + carve(sizeof(float) * QN));
    short* tv      = (short*)(w + carve(2 * 65536));
    short* toa     = (short*)(w + carve(2 * 65536));
    short* tout    = (short*)(w + carve(2 * 65536));
    float* biasOA  = (float*)(w + carve(sizeof(float) * 192));
    unsigned char* vproj = (unsigned char*)(w + carve((size_t)MROW * 256));
    float* offattn = (float*)(w + carve(sizeof(float) * QN * 192));
    float* slots   = (float*)(w + carve(sizeof(float) * QN * 256));

    detect_kernel<<<1, 256, 0, stream>>>((const unsigned char*)mask, flag);
    prep_kernel<<<769, 256, 0, stream>>>(w_value, w_off, w_attn, w_out, b_off, b_attn,
                                         tv, toa, tout, biasOA);
    hit_kernel<<<(QN + 255) / 256, 256, 0, stream>>>(mask, flag, hitv, invc);

    gemm_direct<0><<<MROW / 64, 256, 0, stream>>>(
        value, tv, b_value, nullptr, vproj, MROW);
    gemm_direct<1><<<(QN + 63) / 64, 256, 0, stream>>>(
        query, toa, biasOA, nullptr, offattn, QN);

    sample_kernel<<<2500, 256, 0, stream>>>(
        vproj, offattn, refp, hitv, invc, slots);

    gemm_direct<2><<<(QN + 63) / 64, 256, 0, stream>>>(
        slots, tout, b_out, query, out, QN);
}

// Round 9
// 230.297 us; speedup vs baseline: 1.4339x; 1.4339x over previous
//
#include <hip/hip_runtime.h>
#include <hip/hip_bf16.h>

// SpatialCrossAttention (BEVFormer SCA) fused pipeline for MI355X/gfx950.
//  K0 detect  : infer bev_mask storage layout (u8 / i32 / f32)
//  K1 hit     : hit[c][q], invcnt[q]
//  K2 prep    : bf16 W-fragment tables for the 3 GEMMs (+ concat bias)
//  G* gemm_tab: operand-swapped MFMA GEMM with the WEIGHT TABLE staged in LDS
//               (64KB, 2x32KB double-buffered quarters) -- A rows direct-load.
//  K4 sample  : fused softmax + bilinear gather (HW fp8 cvt) + cam-average
//  G3 gemm<2> : out = slots @ w_out + b_out + query -> d_out f32

typedef __attribute__((ext_vector_type(8))) short short8;
typedef __attribute__((ext_vector_type(4))) float f32x4;
typedef __attribute__((ext_vector_type(2))) float floatx2;

__device__ __forceinline__ short f2bf(float f) {
    union { float f; unsigned u; } c; c.f = f;
    unsigned u = c.u;
    unsigned r = (u + 0x7FFFu + ((u >> 16) & 1u)) >> 16;  // RNE
    return (short)r;
}

// ---- fp8 e4m3fn decode/encode: HW cvt on gfx950, manual fallback ----
__device__ __forceinline__ float e4m3f_manual(unsigned b) {
    unsigned s = (b & 0x80u) << 24;
    unsigned e = (b >> 3) & 15u;
    unsigned m = b & 7u;
    if (e) return __uint_as_float(s | ((e + 120u) << 23) | (m << 20));
    return __uint_as_float(s | __float_as_uint((float)m * 0x1p-9f));
}
__device__ __forceinline__ unsigned char f2e4m3_manual(float x) {
    unsigned u = __float_as_uint(x);
    unsigned s = (u >> 24) & 0x80u;
    float ax = fabsf(x);
    if (!(ax > 0x1p-10f)) return (unsigned char)s;
    if (ax >= 440.f) return (unsigned char)(s | 0x7Eu);
    unsigned au = u & 0x7FFFFFFFu;
    int e = (int)(au >> 23) - 127;
    if (e >= -6) {
        unsigned r = au + 0x7FFFFu + ((au >> 20) & 1u);
        e = (int)(r >> 23) - 127;
        unsigned m = (r >> 20) & 7u;
        if (e > 8) return (unsigned char)(s | 0x7Eu);
        return (unsigned char)(s | (unsigned)((e + 7) << 3) | m);
    } else {
        int m = (int)rintf(ax * 512.f);
        return (unsigned char)(s | (unsigned)m);
    }
}

__device__ __forceinline__ void gload_lds16(const void* g, void* l) {
    __builtin_amdgcn_global_load_lds(
        (const __attribute__((address_space(1))) unsigned*)g,
        (__attribute__((address_space(3))) unsigned*)l, 16, 0, 0);
}

static constexpr int QN   = 10000;
static constexpr int CAMS = 6;
static constexpr int NV   = 23200;   // 116*200
static constexpr int HH   = 116;
static constexpr int WW   = 200;
static constexpr int MROW = CAMS * NV;  // 139200

// ---------------- K0: mask layout detect ----------------
__global__ void detect_kernel(const unsigned char* __restrict__ mask, int* __restrict__ flag) {
    __shared__ unsigned s12[256], s3[256];
    unsigned o12 = 0, o3 = 0;
    for (int i = threadIdx.x; i < 65536; i += 256) {
        unsigned char b = mask[i];
        int m = i & 3;
        if (m == 1 || m == 2) o12 |= b;
        else if (m == 3) o3 |= b;
    }
    s12[threadIdx.x] = o12; s3[threadIdx.x] = o3;
    __syncthreads();
    if (threadIdx.x == 0) {
        unsigned a = 0, b = 0;
        for (int i = 0; i < 256; i++) { a |= s12[i]; b |= s3[i]; }
        *flag = a ? 0 : (b ? 2 : 1);  // 0=u8, 1=i32, 2=f32
    }
}

// ---------------- K1: hit / invcount ----------------
__global__ void hit_kernel(const void* __restrict__ mask, const int* __restrict__ flag,
                           float* __restrict__ hit, float* __restrict__ invcnt) {
    int q = blockIdx.x * 256 + threadIdx.x;
    if (q >= QN) return;
    int f = *flag;
    int cnt = 0;
    for (int c = 0; c < CAMS; c++) {
        bool any = false;
        #pragma unroll
        for (int d = 0; d < 4; d++) {
            size_t i = (size_t)(c * QN + q) * 4 + d;
            bool b;
            if (f == 0)      b = ((const unsigned char*)mask)[i] != 0;
            else if (f == 1) b = ((const int*)mask)[i] != 0;
            else             b = ((const float*)mask)[i] != 0.f;
            any |= b;
        }
        hit[c * QN + q] = any ? 1.f : 0.f;
        cnt += any ? 1 : 0;
    }
    invcnt[q] = 1.f / (float)(cnt > 0 ? cnt : 1);
}

// ---------------- K2: weight fragment tables ----------------
// entry e = ((kc*16 + nt)*64 + lane)*8 + j ;  W[kc*32 + (lane>>4)*8 + j][nt*16 + (lane&15)]
// Used as the MFMA *A-operand*: lane&15 -> n (free dim), (lane>>4)*8+j -> k.
__global__ void prep_kernel(const float* __restrict__ wv, const float* __restrict__ woff,
                            const float* __restrict__ wattn, const float* __restrict__ wout,
                            const float* __restrict__ boff, const float* __restrict__ battn,
                            short* __restrict__ tv, short* __restrict__ toa,
                            short* __restrict__ tout, float* __restrict__ biasOA) {
    int id = blockIdx.x * 256 + threadIdx.x;
    if (id < 3 * 65536) {
        int t = id >> 16;
        int e = id & 65535;
        int j = e & 7, l = (e >> 3) & 63, nt = (e >> 9) & 15, kc = e >> 13;
        int k = kc * 32 + ((l >> 4) << 3) + j;
        int col = nt * 16 + (l & 15);
        float v;
        if (t == 0)      v = wv[k * 256 + col];
        else if (t == 1) v = (col < 128) ? woff[k * 128 + col]
                               : (col < 192 ? wattn[k * 64 + (col - 128)] : 0.f);
        else             v = wout[k * 256 + col];
        short* dst = (t == 0) ? tv : (t == 1) ? toa : tout;
        dst[e] = f2bf(v);
    } else {
        int i = id - 3 * 65536;
        if (i < 192) biasOA[i] = (i < 128) ? boff[i] : battn[i - 128];
    }
}

// ---------------- GEMM: W-table in LDS, operand-swapped, A direct-load ----------------
// out[m][n] = sum_k A[m][k] * W[k][n]  (+bias per mode)
// MFMA D = Afrag(W from LDS) x Bfrag(A-row):
//   A-operand: W fragment, lane&15 -> n, (lane>>4)*8+j -> k
//   B-operand: A[m][k],    lane&15 -> m, (lane>>4)*8+j -> k (8 contiguous f32/lane)
//   D: lane holds 4 consecutive n (nt*16 + (lane>>4)*4 + i) for m = mBase+(lane&15)
// Block = 512 thr / 8 waves x 16 rows = 128 rows. Table: 128KB = 4 quarters
// (2 kc each) double-buffered in 2x32KB LDS; quarter q+1 issued before
// computing quarter q (latency hidden under compute). 4 barriers per block.
// MODE 0: out fp8 e4m3 packed u32 (vproj), MODE 1: f32 192 cols, MODE 2: f32+resid.
template <int MODE>
__global__ __launch_bounds__(512)
void gemm_tab(const float* __restrict__ A, const short* __restrict__ Wtab,
              const float* __restrict__ bias, const float* __restrict__ resid,
              void* __restrict__ out, int M) {
    __shared__ short tab[2][16384];                 // 2 x 32KB
    const int tid = threadIdx.x;
    const int l  = tid & 63;
    const int wv = tid >> 6;                        // 0..7
    const int lr = l & 15;
    const int lg = l >> 4;
    const int mBase = (blockIdx.x * 8 + wv) * 16;
    const int mRow = mBase + lr;
    const int m = min(mRow, M - 1);

    // cooperative: quarter q (32KB = 2 kc) of the table -> buffer b
    auto load_q = [&](int b, int q) {
        #pragma unroll
        for (int it = 0; it < 4; it++) {
            int linear = (it * 512 + tid) * 16;     // byte 0..32767
            const char* src = (const char*)Wtab + q * 32768 + linear;
            char* dst = (char*)&tab[b][0] + it * 8192 + (tid & 448) * 16;  // wave-uniform
            gload_lds16(src, dst);
        }
    };

    f32x4 acc[16] = {};
    const float* arow = A + (size_t)m * 256 + lg * 8;

    // compute 2 kc steps (one quarter) from buffer b
    auto compute_q = [&](int b, int kc0) {
        #pragma unroll
        for (int kk = 0; kk < 2; kk++) {
            const float4* p = (const float4*)(arow + (kc0 + kk) * 32);
            float4 x0 = p[0], x1 = p[1];
            unsigned u0, u1, u2, u3;
            asm("v_cvt_pk_bf16_f32 %0, %1, %2" : "=v"(u0) : "v"(x0.x), "v"(x0.y));
            asm("v_cvt_pk_bf16_f32 %0, %1, %2" : "=v"(u1) : "v"(x0.z), "v"(x0.w));
            asm("v_cvt_pk_bf16_f32 %0, %1, %2" : "=v"(u2) : "v"(x1.x), "v"(x1.y));
            asm("v_cvt_pk_bf16_f32 %0, %1, %2" : "=v"(u3) : "v"(x1.z), "v"(x1.w));
            union { unsigned u[4]; short8 s8; } uu;
            uu.u[0] = u0; uu.u[1] = u1; uu.u[2] = u2; uu.u[3] = u3;
            short8 bfrag = uu.s8;
            #pragma unroll
            for (int nt = 0; nt < 16; nt++) {
                if (MODE == 1 && nt >= 12) continue;
                short8 af = *(const short8*)(&tab[b][(kk * 16 + nt) * 512 + l * 8]);
                acc[nt] = __builtin_amdgcn_mfma_f32_16x16x32_bf16(af, bfrag, acc[nt], 0, 0, 0);
            }
        }
    };

    load_q(0, 0);
    __syncthreads();                 // q0 visible
    load_q(1, 1);                    // issue q1 (completes under compute)
    compute_q(0, 0);                 // kc 0,1
    __syncthreads();                 // q1 visible; all done reading buf0
    load_q(0, 2);                    // issue q2
    compute_q(1, 2);                 // kc 2,3
    __syncthreads();                 // q2 visible; all done reading buf1
    load_q(1, 3);                    // issue q3
    compute_q(0, 4);                 // kc 4,5
    __syncthreads();                 // q3 visible; all done reading buf0
    compute_q(1, 6);                 // kc 6,7

    if (mRow < M) {
        #pragma unroll
        for (int nt = 0; nt < 16; nt++) {
            if (MODE == 1 && nt >= 12) continue;
            int n0 = nt * 16 + lg * 4;            // 4 consecutive n
            float4 bv = *(const float4*)(bias + n0);
            float v0 = acc[nt][0] + bv.x, v1 = acc[nt][1] + bv.y;
            float v2 = acc[nt][2] + bv.z, v3 = acc[nt][3] + bv.w;
            if (MODE == 0) {
                unsigned pk;
#if __has_builtin(__builtin_amdgcn_cvt_pk_fp8_f32)
                pk = __builtin_amdgcn_cvt_pk_fp8_f32(v0, v1, 0, false);
                pk = __builtin_amdgcn_cvt_pk_fp8_f32(v2, v3, pk, true);
#else
                pk = (unsigned)f2e4m3_manual(v0) | ((unsigned)f2e4m3_manual(v1) << 8)
                   | ((unsigned)f2e4m3_manual(v2) << 16) | ((unsigned)f2e4m3_manual(v3) << 24);
#endif
                ((unsigned*)out)[(size_t)mRow * 64 + (n0 >> 2)] = pk;
            } else if (MODE == 1) {
                float4 o; o.x = v0; o.y = v1; o.z = v2; o.w = v3;
                *(float4*)((float*)out + (size_t)mRow * 192 + n0) = o;
            } else {
                float4 rz = *(const float4*)(resid + (size_t)mRow * 256 + n0);
                float4 o; o.x = v0 + rz.x; o.y = v1 + rz.y; o.z = v2 + rz.z; o.w = v3 + rz.w;
                *(float4*)((float*)out + (size_t)mRow * 256 + n0) = o;
            }
        }
    }
}

// ---------------- K4: fused softmax + bilinear sample (HW fp8) + cam average ----------------
// unit = 8 lanes per (q,h); lane sub handles DH elems sub*4..sub*4+3 (4 fp8 bytes).
// XCD-chunked swizzle for L2 locality.
__global__ __launch_bounds__(256)
void sample_kernel(const unsigned char* __restrict__ vproj, const float* __restrict__ offattn,
                   const float* __restrict__ refp, const float* __restrict__ hit,
                   const float* __restrict__ invcnt, float* __restrict__ slots) {
    // chunked-bijective XCD swizzle: nwg=2500, 8 XCDs -> q_=312, r=4
    int bid = blockIdx.x;
    int xcd = bid & 7, idx = bid >> 3;
    const int qch = 312, rch = 4;
    int start = (xcd < rch) ? xcd * (qch + 1) : rch * (qch + 1) + (xcd - rch) * qch;
    int wg = start + idx;

    int tid = threadIdx.x;
    int unit = wg * 32 + (tid >> 3);
    int sub = tid & 7;
    int q = unit >> 3;
    int h = unit & 7;

    const float* oa = offattn + (size_t)q * 192;
    float ox[8], oy[8], aw[8];
    float m = -1e30f;
    #pragma unroll
    for (int p = 0; p < 8; p++) {
        ox[p] = oa[h * 16 + 2 * p];
        oy[p] = oa[h * 16 + 2 * p + 1];
        float lg = oa[128 + h * 8 + p];
        aw[p] = lg;
        m = fmaxf(m, lg);
    }
    float s = 0.f;
    #pragma unroll
    for (int p = 0; p < 8; p++) { aw[p] = __expf(aw[p] - m); s += aw[p]; }
    float is = 1.f / s;
    #pragma unroll
    for (int p = 0; p < 8; p++) aw[p] *= is;

    float a0 = 0.f, a1 = 0.f, a2 = 0.f, a3 = 0.f;
    const unsigned char* vb = vproj + h * 32 + sub * 4;

    auto acc4 = [&](unsigned u, float w) {
#if __has_builtin(__builtin_amdgcn_cvt_pk_f32_fp8)
        floatx2 lo = __builtin_amdgcn_cvt_pk_f32_fp8((int)u, false);
        floatx2 hi = __builtin_amdgcn_cvt_pk_f32_fp8((int)u, true);
        a0 = fmaf(w, lo.x, a0); a1 = fmaf(w, lo.y, a1);
        a2 = fmaf(w, hi.x, a2); a3 = fmaf(w, hi.y, a3);
#else
        a0 = fmaf(w, e4m3f_manual(u & 255), a0);
        a1 = fmaf(w, e4m3f_manual((u >> 8) & 255), a1);
        a2 = fmaf(w, e4m3f_manual((u >> 16) & 255), a2);
        a3 = fmaf(w, e4m3f_manual(u >> 24), a3);
#endif
    };

    for (int c = 0; c < CAMS; c++) {
        if (hit[c * QN + q] == 0.f) continue;
        const float* rp = refp + (size_t)(c * QN + q) * 8;
        float rx[4], ry[4];
        #pragma unroll
        for (int d = 0; d < 4; d++) {
            rx[d] = rp[2 * d]     * (float)WW - 0.5f;
            ry[d] = rp[2 * d + 1] * (float)HH - 0.5f;
        }
        const unsigned char* vc = vb + (size_t)c * (NV * 256);
        #pragma unroll
        for (int p = 0; p < 8; p++) {
            float x = rx[p & 3] + ox[p];
            float y = ry[p & 3] + oy[p];
            float xf = floorf(x), yf = floorf(y);
            float fx = x - xf, fy = y - yf;
            int x0 = (int)xf, y0 = (int)yf;
            int xc0 = min(max(x0, 0), WW - 1), xc1 = min(max(x0 + 1, 0), WW - 1);
            int yc0 = min(max(y0, 0), HH - 1), yc1 = min(max(y0 + 1, 0), HH - 1);
            float vx0 = ((unsigned)x0 < (unsigned)WW) ? 1.f : 0.f;
            float vx1 = ((unsigned)(x0 + 1) < (unsigned)WW) ? 1.f : 0.f;
            float vy0 = ((unsigned)y0 < (unsigned)HH) ? 1.f : 0.f;
            float vy1 = ((unsigned)(y0 + 1) < (unsigned)HH) ? 1.f : 0.f;
            float wp = aw[p];
            float wx0 = (1.f - fx) * vx0 * wp, wx1 = fx * vx1 * wp;
            float wy0 = (1.f - fy) * vy0,      wy1 = fy * vy1;
            unsigned u00 = *(const unsigned*)(vc + (size_t)(yc0 * WW + xc0) * 256);
            unsigned u10 = *(const unsigned*)(vc + (size_t)(yc0 * WW + xc1) * 256);
            unsigned u01 = *(const unsigned*)(vc + (size_t)(yc1 * WW + xc0) * 256);
            unsigned u11 = *(const unsigned*)(vc + (size_t)(yc1 * WW + xc1) * 256);
            acc4(u00, wx0 * wy0);
            acc4(u10, wx1 * wy0);
            acc4(u01, wx0 * wy1);
            acc4(u11, wx1 * wy1);
        }
    }
    float ic = invcnt[q];
    float* sp = slots + (size_t)q * 256 + h * 32 + sub * 4;
    float4 o; o.x = a0 * ic; o.y = a1 * ic; o.z = a2 * ic; o.w = a3 * ic;
    *(float4*)sp = o;
}

extern "C" void kernel_launch(void* const* d_in, const int* in_sizes, int n_in,
                              void* d_out, int out_size, void* d_ws, size_t ws_size,
                              hipStream_t stream) {
    const float* query   = (const float*)d_in[0];
    const float* value   = (const float*)d_in[2];
    const float* refp    = (const float*)d_in[3];
    const void*  mask    = d_in[4];
    const float* w_value = (const float*)d_in[7];
    const float* b_value = (const float*)d_in[8];
    const float* w_off   = (const float*)d_in[9];
    const float* b_off   = (const float*)d_in[10];
    const float* w_attn  = (const float*)d_in[11];
    const float* b_attn  = (const float*)d_in[12];
    const float* w_out   = (const float*)d_in[13];
    const float* b_out   = (const float*)d_in[14];
    float* out = (float*)d_out;

    char* w = (char*)d_ws;
    size_t o = 0;
    auto carve = [&](size_t bytes) { size_t r = o; o = (o + bytes + 255) & ~(size_t)255; return r; };
    int*   flag    = (int*)  (w + carve(4));
    float* hitv    = (float*)(w + carve(sizeof(float) * CAMS * QN));
    float* invc    = (float*)(w + carve(sizeof(float) * QN));
    short* tv      = (short*)(w + carve(2 * 65536));
    short* toa     = (short*)(w + carve(2 * 65536));
    short* tout    = (short*)(w + carve(2 * 65536));
    float* biasOA  = (float*)(w + carve(sizeof(float) * 192));
    unsigned char* vproj = (unsigned char*)(w + carve((size_t)MROW * 256));
    float* offattn = (float*)(w + carve(sizeof(float) * QN * 192));
    float* slots   = (float*)(w + carve(sizeof(float) * QN * 256));

    detect_kernel<<<1, 256, 0, stream>>>((const unsigned char*)mask, flag);
    prep_kernel<<<769, 256, 0, stream>>>(w_value, w_off, w_attn, w_out, b_off, b_attn,
                                         tv, toa, tout, biasOA);
    hit_kernel<<<(QN + 255) / 256, 256, 0, stream>>>(mask, flag, hitv, invc);

    gemm_tab<0><<<(MROW + 127) / 128, 512, 0, stream>>>(
        value, tv, b_value, nullptr, vproj, MROW);
    gemm_tab<1><<<(QN + 127) / 128, 512, 0, stream>>>(
        query, toa, biasOA, nullptr, offattn, QN);

    sample_kernel<<<2500, 256, 0, stream>>>(
        vproj, offattn, refp, hitv, invc, slots);

    gemm_tab<2><<<(QN + 127) / 128, 512, 0, stream>>>(
        slots, tout, b_out, query, out, QN);
}

// Round 10
// 212.066 us; speedup vs baseline: 1.5572x; 1.0860x over previous
//
#include <hip/hip_runtime.h>
#include <hip/hip_bf16.h>

// SpatialCrossAttention (BEVFormer SCA) fused pipeline for MI355X/gfx950.
//  K0 detect  : infer bev_mask storage layout (u8 / i32 / f32)
//  K1 hit     : hit[c][q], invcnt[q]
//  K2 prep    : bf16 W-fragment tables for the 3 GEMMs (+ concat bias)
//  gemm_v/oa/out: operand-swapped MFMA GEMM, weight table staged in LDS
//               (2x32KB double-buffered quarters), A rows direct-load.
//  K4 sample  : fused softmax + bilinear gather (HW fp8 cvt) + cam-average
//               2x2 BEV-tile block mapping + XCD chunk swizzle for L2 locality
__device__ __forceinline__ void gload_lds16(const void* g, void* l) {
    __builtin_amdgcn_global_load_lds(
        (const __attribute__((address_space(1))) unsigned*)g,
        (__attribute__((address_space(3))) unsigned*)l, 16, 0, 0);
}

typedef __attribute__((ext_vector_type(8))) short short8;
typedef __attribute__((ext_vector_type(4))) float f32x4;
typedef __attribute__((ext_vector_type(2))) float floatx2;

__device__ __forceinline__ short f2bf(float f) {
    union { float f; unsigned u; } c; c.f = f;
    unsigned u = c.u;
    unsigned r = (u + 0x7FFFu + ((u >> 16) & 1u)) >> 16;  // RNE
    return (short)r;
}

// ---- fp8 e4m3fn decode/encode: HW cvt on gfx950, manual fallback ----
__device__ __forceinline__ float e4m3f_manual(unsigned b) {
    unsigned s = (b & 0x80u) << 24;
    unsigned e = (b >> 3) & 15u;
    unsigned m = b & 7u;
    if (e) return __uint_as_float(s | ((e + 120u) << 23) | (m << 20));
    return __uint_as_float(s | __float_as_uint((float)m * 0x1p-9f));
}
__device__ __forceinline__ unsigned char f2e4m3_manual(float x) {
    unsigned u = __float_as_uint(x);
    unsigned s = (u >> 24) & 0x80u;
    float ax = fabsf(x);
    if (!(ax > 0x1p-10f)) return (unsigned char)s;
    if (ax >= 440.f) return (unsigned char)(s | 0x7Eu);
    unsigned au = u & 0x7FFFFFFFu;
    int e = (int)(au >> 23) - 127;
    if (e >= -6) {
        unsigned r = au + 0x7FFFFu + ((au >> 20) & 1u);
        e = (int)(r >> 23) - 127;
        unsigned m = (r >> 20) & 7u;
        if (e > 8) return (unsigned char)(s | 0x7Eu);
        return (unsigned char)(s | (unsigned)((e + 7) << 3) | m);
    } else {
        int m = (int)rintf(ax * 512.f);
        return (unsigned char)(s | (unsigned)m);
    }
}

static constexpr int QN   = 10000;
static constexpr int CAMS = 6;
static constexpr int NV   = 23200;   // 116*200
static constexpr int HH   = 116;
static constexpr int WW   = 200;
static constexpr int MROW = CAMS * NV;  // 139200

// ---------------- K0: mask layout detect (16KB scan) ----------------
__global__ void detect_kernel(const unsigned char* __restrict__ mask, int* __restrict__ flag) {
    __shared__ unsigned s12[256], s3[256];
    unsigned o12 = 0, o3 = 0;
    for (int i = threadIdx.x; i < 16384; i += 256) {
        unsigned char b = mask[i];
        int m = i & 3;
        if (m == 1 || m == 2) o12 |= b;
        else if (m == 3) o3 |= b;
    }
    s12[threadIdx.x] = o12; s3[threadIdx.x] = o3;
    __syncthreads();
    if (threadIdx.x == 0) {
        unsigned a = 0, b = 0;
        for (int i = 0; i < 256; i++) { a |= s12[i]; b |= s3[i]; }
        *flag = a ? 0 : (b ? 2 : 1);  // 0=u8, 1=i32, 2=f32
    }
}

// ---------------- K1: hit / invcount ----------------
__global__ void hit_kernel(const void* __restrict__ mask, const int* __restrict__ flag,
                           float* __restrict__ hit, float* __restrict__ invcnt) {
    int q = blockIdx.x * 256 + threadIdx.x;
    if (q >= QN) return;
    int f = *flag;
    int cnt = 0;
    for (int c = 0; c < CAMS; c++) {
        bool any = false;
        #pragma unroll
        for (int d = 0; d < 4; d++) {
            size_t i = (size_t)(c * QN + q) * 4 + d;
            bool b;
            if (f == 0)      b = ((const unsigned char*)mask)[i] != 0;
            else if (f == 1) b = ((const int*)mask)[i] != 0;
            else             b = ((const float*)mask)[i] != 0.f;
            any |= b;
        }
        hit[c * QN + q] = any ? 1.f : 0.f;
        cnt += any ? 1 : 0;
    }
    invcnt[q] = 1.f / (float)(cnt > 0 ? cnt : 1);
}

// ---------------- K2: weight fragment tables ----------------
// entry e = ((kc*16 + nt)*64 + lane)*8 + j ;  W[kc*32 + (lane>>4)*8 + j][nt*16 + (lane&15)]
__global__ void prep_kernel(const float* __restrict__ wv, const float* __restrict__ woff,
                            const float* __restrict__ wattn, const float* __restrict__ wout,
                            const float* __restrict__ boff, const float* __restrict__ battn,
                            short* __restrict__ tv, short* __restrict__ toa,
                            short* __restrict__ tout, float* __restrict__ biasOA) {
    int id = blockIdx.x * 256 + threadIdx.x;
    if (id < 3 * 65536) {
        int t = id >> 16;
        int e = id & 65535;
        int j = e & 7, l = (e >> 3) & 63, nt = (e >> 9) & 15, kc = e >> 13;
        int k = kc * 32 + ((l >> 4) << 3) + j;
        int col = nt * 16 + (l & 15);
        float v;
        if (t == 0)      v = wv[k * 256 + col];
        else if (t == 1) v = (col < 128) ? woff[k * 128 + col]
                               : (col < 192 ? wattn[k * 64 + (col - 128)] : 0.f);
        else             v = wout[k * 256 + col];
        short* dst = (t == 0) ? tv : (t == 1) ? toa : tout;
        dst[e] = f2bf(v);
    } else {
        int i = id - 3 * 65536;
        if (i < 192) biasOA[i] = (i < 128) ? boff[i] : battn[i - 128];
    }
}

// ---------------- GEMM body: W-table in LDS, operand-swapped, A direct-load ----------------
// out[m][n] = sum_k A[m][k] * W[k][n]  (+bias per mode)
// Block = 512 thr / 8 waves x 16 rows = 128 rows. Table: 128KB = 4 quarters
// (2 kc each) double-buffered in 2x32KB LDS. 4 barriers per block.
// MODE 0: fp8 packed u32 out; MODE 1: f32 192 cols; MODE 2: f32 + resid.
template <int MODE>
__device__ __forceinline__
void gemm_tab_body(const float* __restrict__ A, const short* __restrict__ Wtab,
                   const float* __restrict__ bias, const float* __restrict__ resid,
                   void* __restrict__ out, int M) {
    __shared__ short tab[2][16384];                 // 2 x 32KB
    const int tid = threadIdx.x;
    const int l  = tid & 63;
    const int wv = tid >> 6;                        // 0..7
    const int lr = l & 15;
    const int lg = l >> 4;
    const int mBase = (blockIdx.x * 8 + wv) * 16;
    const int mRow = mBase + lr;
    const int m = min(mRow, M - 1);

    auto load_q = [&](int b, int q) {
        #pragma unroll
        for (int it = 0; it < 4; it++) {
            int linear = (it * 512 + tid) * 16;     // byte 0..32767
            const char* src = (const char*)Wtab + q * 32768 + linear;
            char* dst = (char*)&tab[b][0] + it * 8192 + (tid & 448) * 16;  // wave-uniform
            gload_lds16(src, dst);
        }
    };

    f32x4 acc[16] = {};
    const float* arow = A + (size_t)m * 256 + lg * 8;

    auto compute_q = [&](int b, int kc0) {
        #pragma unroll
        for (int kk = 0; kk < 2; kk++) {
            const float4* p = (const float4*)(arow + (kc0 + kk) * 32);
            float4 x0 = p[0], x1 = p[1];
            unsigned u0, u1, u2, u3;
            asm("v_cvt_pk_bf16_f32 %0, %1, %2" : "=v"(u0) : "v"(x0.x), "v"(x0.y));
            asm("v_cvt_pk_bf16_f32 %0, %1, %2" : "=v"(u1) : "v"(x0.z), "v"(x0.w));
            asm("v_cvt_pk_bf16_f32 %0, %1, %2" : "=v"(u2) : "v"(x1.x), "v"(x1.y));
            asm("v_cvt_pk_bf16_f32 %0, %1, %2" : "=v"(u3) : "v"(x1.z), "v"(x1.w));
            union { unsigned u[4]; short8 s8; } uu;
            uu.u[0] = u0; uu.u[1] = u1; uu.u[2] = u2; uu.u[3] = u3;
            short8 bfrag = uu.s8;
            #pragma unroll
            for (int nt = 0; nt < 16; nt++) {
                if (MODE == 1 && nt >= 12) continue;
                short8 af = *(const short8*)(&tab[b][(kk * 16 + nt) * 512 + l * 8]);
                acc[nt] = __builtin_amdgcn_mfma_f32_16x16x32_bf16(af, bfrag, acc[nt], 0, 0, 0);
            }
        }
    };

    load_q(0, 0);
    __syncthreads();                 // q0 visible
    load_q(1, 1);
    compute_q(0, 0);                 // kc 0,1
    __syncthreads();                 // q1 visible
    load_q(0, 2);
    compute_q(1, 2);                 // kc 2,3
    __syncthreads();                 // q2 visible
    load_q(1, 3);
    compute_q(0, 4);                 // kc 4,5
    __syncthreads();                 // q3 visible
    compute_q(1, 6);                 // kc 6,7

    if (mRow < M) {
        #pragma unroll
        for (int nt = 0; nt < 16; nt++) {
            if (MODE == 1 && nt >= 12) continue;
            int n0 = nt * 16 + lg * 4;
            float4 bv = *(const float4*)(bias + n0);
            float v0 = acc[nt][0] + bv.x, v1 = acc[nt][1] + bv.y;
            float v2 = acc[nt][2] + bv.z, v3 = acc[nt][3] + bv.w;
            if (MODE == 0) {
                unsigned pk;
#if __has_builtin(__builtin_amdgcn_cvt_pk_fp8_f32)
                pk = __builtin_amdgcn_cvt_pk_fp8_f32(v0, v1, 0, false);
                pk = __builtin_amdgcn_cvt_pk_fp8_f32(v2, v3, pk, true);
#else
                pk = (unsigned)f2e4m3_manual(v0) | ((unsigned)f2e4m3_manual(v1) << 8)
                   | ((unsigned)f2e4m3_manual(v2) << 16) | ((unsigned)f2e4m3_manual(v3) << 24);
#endif
                ((unsigned*)out)[(size_t)mRow * 64 + (n0 >> 2)] = pk;
            } else if (MODE == 1) {
                float4 o; o.x = v0; o.y = v1; o.z = v2; o.w = v3;
                *(float4*)((float*)out + (size_t)mRow * 192 + n0) = o;
            } else {
                float4 rz = *(const float4*)(resid + (size_t)mRow * 256 + n0);
                float4 o; o.x = v0 + rz.x; o.y = v1 + rz.y; o.z = v2 + rz.z; o.w = v3 + rz.w;
                *(float4*)((float*)out + (size_t)mRow * 256 + n0) = o;
            }
        }
    }
}

// Distinctly-named instantiations for rocprof visibility.
__global__ __launch_bounds__(512)
void gemm_v(const float* __restrict__ A, const short* __restrict__ Wtab,
            const float* __restrict__ bias, void* __restrict__ out, int M) {
    gemm_tab_body<0>(A, Wtab, bias, nullptr, out, M);
}
__global__ __launch_bounds__(512)
void gemm_oa(const float* __restrict__ A, const short* __restrict__ Wtab,
             const float* __restrict__ bias, void* __restrict__ out, int M) {
    gemm_tab_body<1>(A, Wtab, bias, nullptr, out, M);
}
__global__ __launch_bounds__(512)
void gemm_out(const float* __restrict__ A, const short* __restrict__ Wtab,
              const float* __restrict__ bias, const float* __restrict__ resid,
              void* __restrict__ out, int M) {
    gemm_tab_body<2>(A, Wtab, bias, resid, out, M);
}

// ---------------- K4: fused softmax + bilinear sample (HW fp8) + cam average ----------------
// unit = 8 lanes per (q,h). Block covers a 2x2 BEV tile (4 q x 8 h = 32 units).
// Q assumed 100x100 raster; mapping is a bijection so correctness never depends on it.
// XCD-chunked swizzle over tiles for per-XCD L2 locality.
__global__ __launch_bounds__(256)
void sample_kernel(const unsigned char* __restrict__ vproj, const float* __restrict__ offattn,
                   const float* __restrict__ refp, const float* __restrict__ hit,
                   const float* __restrict__ invcnt, float* __restrict__ slots) {
    // chunked-bijective XCD swizzle: nwg=2500, 8 XCDs -> q_=312, r=4
    int bid = blockIdx.x;
    int xcd = bid & 7, idx = bid >> 3;
    const int qch = 312, rch = 4;
    int start = (xcd < rch) ? xcd * (qch + 1) : rch * (qch + 1) + (xcd - rch) * qch;
    int wg = start + idx;

    // 2x2 BEV tile: wg -> tile (row2, col2); 4 q per block
    int row2 = wg / 50, col2 = wg % 50;

    int tid = threadIdx.x;
    int unit = tid >> 3;              // 0..31
    int sub = tid & 7;
    int qi = unit >> 3;               // 0..3 within tile
    int h = unit & 7;
    int q = (row2 * 2 + (qi >> 1)) * 100 + col2 * 2 + (qi & 1);

    const float* oa = offattn + (size_t)q * 192;
    float ox[8], oy[8], aw[8];
    float m = -1e30f;
    #pragma unroll
    for (int p = 0; p < 8; p++) {
        ox[p] = oa[h * 16 + 2 * p];
        oy[p] = oa[h * 16 + 2 * p + 1];
        float lg = oa[128 + h * 8 + p];
        aw[p] = lg;
        m = fmaxf(m, lg);
    }
    float s = 0.f;
    #pragma unroll
    for (int p = 0; p < 8; p++) { aw[p] = __expf(aw[p] - m); s += aw[p]; }
    float is = 1.f / s;
    #pragma unroll
    for (int p = 0; p < 8; p++) aw[p] *= is;

    float a0 = 0.f, a1 = 0.f, a2 = 0.f, a3 = 0.f;
    const unsigned char* vb = vproj + h * 32 + sub * 4;

    auto acc4 = [&](unsigned u, float w) {
#if __has_builtin(__builtin_amdgcn_cvt_pk_f32_fp8)
        floatx2 lo = __builtin_amdgcn_cvt_pk_f32_fp8((int)u, false);
        floatx2 hi = __builtin_amdgcn_cvt_pk_f32_fp8((int)u, true);
        a0 = fmaf(w, lo.x, a0); a1 = fmaf(w, lo.y, a1);
        a2 = fmaf(w, hi.x, a2); a3 = fmaf(w, hi.y, a3);
#else
        a0 = fmaf(w, e4m3f_manual(u & 255), a0);
        a1 = fmaf(w, e4m3f_manual((u >> 8) & 255), a1);
        a2 = fmaf(w, e4m3f_manual((u >> 16) & 255), a2);
        a3 = fmaf(w, e4m3f_manual(u >> 24), a3);
#endif
    };

    for (int c = 0; c < CAMS; c++) {
        if (hit[c * QN + q] == 0.f) continue;
        const float* rp = refp + (size_t)(c * QN + q) * 8;
        float rx[4], ry[4];
        #pragma unroll
        for (int d = 0; d < 4; d++) {
            rx[d] = rp[2 * d]     * (float)WW - 0.5f;
            ry[d] = rp[2 * d + 1] * (float)HH - 0.5f;
        }
        const unsigned char* vc = vb + (size_t)c * (NV * 256);
        #pragma unroll
        for (int p = 0; p < 8; p++) {
            float x = rx[p & 3] + ox[p];
            float y = ry[p & 3] + oy[p];
            float xf = floorf(x), yf = floorf(y);
            float fx = x - xf, fy = y - yf;
            int x0 = (int)xf, y0 = (int)yf;
            int xc0 = min(max(x0, 0), WW - 1), xc1 = min(max(x0 + 1, 0), WW - 1);
            int yc0 = min(max(y0, 0), HH - 1), yc1 = min(max(y0 + 1, 0), HH - 1);
            float vx0 = ((unsigned)x0 < (unsigned)WW) ? 1.f : 0.f;
            float vx1 = ((unsigned)(x0 + 1) < (unsigned)WW) ? 1.f : 0.f;
            float vy0 = ((unsigned)y0 < (unsigned)HH) ? 1.f : 0.f;
            float vy1 = ((unsigned)(y0 + 1) < (unsigned)HH) ? 1.f : 0.f;
            float wp = aw[p];
            float wx0 = (1.f - fx) * vx0 * wp, wx1 = fx * vx1 * wp;
            float wy0 = (1.f - fy) * vy0,      wy1 = fy * vy1;
            unsigned u00 = *(const unsigned*)(vc + (size_t)(yc0 * WW + xc0) * 256);
            unsigned u10 = *(const unsigned*)(vc + (size_t)(yc0 * WW + xc1) * 256);
            unsigned u01 = *(const unsigned*)(vc + (size_t)(yc1 * WW + xc0) * 256);
            unsigned u11 = *(const unsigned*)(vc + (size_t)(yc1 * WW + xc1) * 256);
            acc4(u00, wx0 * wy0);
            acc4(u10, wx1 * wy0);
            acc4(u01, wx0 * wy1);
            acc4(u11, wx1 * wy1);
        }
    }
    float ic = invcnt[q];
    float* sp = slots + (size_t)q * 256 + h * 32 + sub * 4;
    float4 o; o.x = a0 * ic; o.y = a1 * ic; o.z = a2 * ic; o.w = a3 * ic;
    *(float4*)sp = o;
}

extern "C" void kernel_launch(void* const* d_in, const int* in_sizes, int n_in,
                              void* d_out, int out_size, void* d_ws, size_t ws_size,
                              hipStream_t stream) {
    const float* query   = (const float*)d_in[0];
    const float* value   = (const float*)d_in[2];
    const float* refp    = (const float*)d_in[3];
    const void*  mask    = d_in[4];
    const float* w_value = (const float*)d_in[7];
    const float* b_value = (const float*)d_in[8];
    const float* w_off   = (const float*)d_in[9];
    const float* b_off   = (const float*)d_in[10];
    const float* w_attn  = (const float*)d_in[11];
    const float* b_attn  = (const float*)d_in[12];
    const float* w_out   = (const float*)d_in[13];
    const float* b_out   = (const float*)d_in[14];
    float* out = (float*)d_out;

    char* w = (char*)d_ws;
    size_t o = 0;
    auto carve = [&](size_t bytes) { size_t r = o; o = (o + bytes + 255) & ~(size_t)255; return r; };
    int*   flag    = (int*)  (w + carve(4));
    float* hitv    = (float*)(w + carve(sizeof(float) * CAMS * QN));
    float* invc    = (float*)(w + carve(sizeof(float) * QN));
    short* tv      = (short*)(w + carve(2 * 65536));
    short* toa     = (short*)(w + carve(2 * 65536));
    short* tout    = (short*)(w + carve(2 * 65536));
    float* biasOA  = (float*)(w + carve(sizeof(float) * 192));
    unsigned char* vproj = (unsigned char*)(w + carve((size_t)MROW * 256));
    float* offattn = (float*)(w + carve(sizeof(float) * QN * 192));
    float* slots   = (float*)(w + carve(sizeof(float) * QN * 256));

    detect_kernel<<<1, 256, 0, stream>>>((const unsigned char*)mask, flag);
    prep_kernel<<<769, 256, 0, stream>>>(w_value, w_off, w_attn, w_out, b_off, b_attn,
                                         tv, toa, tout, biasOA);
    hit_kernel<<<(QN + 255) / 256, 256, 0, stream>>>(mask, flag, hitv, invc);

    gemm_v<<<(MROW + 127) / 128, 512, 0, stream>>>(value, tv, b_value, vproj, MROW);
    gemm_oa<<<(QN + 127) / 128, 512, 0, stream>>>(query, toa, biasOA, offattn, QN);

    sample_kernel<<<2500, 256, 0, stream>>>(
        vproj, offattn, refp, hitv, invc, slots);

    gemm_out<<<(QN + 127) / 128, 512, 0, stream>>>(slots, tout, b_out, query, out, QN);
}